// Round 13
// baseline (508.876 us; speedup 1.0000x reference)
//
#include <hip/hip_runtime.h>

// ---------------------------------------------------------------------------
// SNN forward, split-phase v5.2.
// wsum (parallel over t, LDS-LUT conv / MFMA fc) + scan (serial LIF).
// T16-tiled wsum slabs. v5.2: sector-perfect writes WITHOUT LDS staging —
// each thread accumulates 8 consecutive t in registers and stores two
// float4s (one aligned 32B sector of its neuron's tile). Round-12 PMC:
// staging fixed write amplification but its 62KB LDS dropped occupancy to
// 22.5% and made wsum1 slower (69->76us).
// ---------------------------------------------------------------------------

#define THETA 5120.0f

typedef __attribute__((ext_vector_type(8))) short bfrag;   // 8 bf16 (4 VGPRs)
typedef __attribute__((ext_vector_type(4))) float ffrag;   // 4 f32 acc

__device__ __forceinline__ float dyn_step(float x, float& u, float& v, float& r) {
#pragma clang fp contract(off)
    u = 0.75f * u + 64.0f * x;          // current decay (1024/4096), W_SCALE=64
    float vn = 0.96875f * v + u;        // voltage decay (128/4096)
    vn = (r > 0.0f) ? 0.0f : vn;        // refractory clamp
    float s;
    if (vn >= THETA) { s = 1.0f; v = 0.0f; r = 1.0f; }
    else             { s = 0.0f; v = vn; r = fmaxf(r - 1.0f, 0.0f); }
    return s;
}

__device__ __forceinline__ float dpp_add_xor1(float x) {
    int y = __builtin_amdgcn_update_dpp(0, __float_as_int(x), 0xB1, 0xF, 0xF, true);
    return x + __int_as_float(y);
}
__device__ __forceinline__ float dpp_add_xor2(float x) {
    int y = __builtin_amdgcn_update_dpp(0, __float_as_int(x), 0x4E, 0xF, 0xF, true);
    return x + __int_as_float(y);
}

// compress bits at positions 4k (k=0..15) of a 64-bit word into 16 bits
__device__ __forceinline__ unsigned int compress4(unsigned long long x) {
    x &= 0x1111111111111111ull;
    x = (x | (x >> 3))  & 0x0303030303030303ull;
    x = (x | (x >> 6))  & 0x000F000F000F000Full;
    x = (x | (x >> 12)) & 0x000000FF000000FFull;
    x = (x | (x >> 24)) & 0xFFFFull;
    return (unsigned int)x;
}

__device__ __forceinline__ unsigned short f2bf(float f) {
    unsigned int u = __float_as_uint(f);
    unsigned int r = (u + 0x7FFFu + ((u >> 16) & 1u)) >> 16;   // RNE
    return (unsigned short)r;
}
__device__ __forceinline__ float bf2f(unsigned short b) {
    return __uint_as_float(((unsigned int)b) << 16);
}

__device__ __forceinline__ float f4_elem(float4 v, int j) {
    return (j == 0) ? v.x : (j == 1) ? v.y : (j == 2) ? v.z : v.w;
}

// ---------------------------------------------------------------------------
// k_masks: in [B=48,C=4,26,26,T=128] f32 -> xb uint2[t][b][pr][28 rows]
// ---------------------------------------------------------------------------
__global__ __launch_bounds__(256) void k_masks(const float* __restrict__ in,
                                               uint2* __restrict__ xb) {
    int wv = blockIdx.x * 4 + (threadIdx.x >> 6);
    int lane = threadIdx.x & 63;
    int y = wv % 26; int r = wv / 26;
    int pr = r & 1; int b = r >> 1;
    int ch = lane >> 5;
    int x = lane & 31;
    int act = x < 26;
    int xc = act ? x : 25;
    const float4* src = (const float4*)(in + (size_t)(((b * 4 + pr * 2 + ch) * 26 + y) * 26 + xc) * 128);
    uint2* dst = xb + ((size_t)b * 2 + pr) * 28 + (y + 1);
    for (int t4 = 0; t4 < 32; ++t4) {
        float4 f = src[t4];
#pragma unroll
        for (int k = 0; k < 4; ++k) {
            float fv = f4_elem(f, k);
            unsigned long long bal = __ballot(act && (fv != 0.0f));
            if (lane == 0) {
                unsigned int lo = ((unsigned int)bal & 0x03FFFFFFu) << 1;
                unsigned int hi = ((unsigned int)(bal >> 32) & 0x03FFFFFFu) << 1;
                dst[(size_t)(t4 * 4 + k) * 2688] = make_uint2(lo, hi);
            }
        }
    }
}

// ---------------------------------------------------------------------------
// k_wsum1: conv1 wsum (4->8ch, 5x5, 26->24), oc half H. LUT 10-bit windows
// at lo + 33*hi. Block 576 = one (b,oc) image; t-chunk 32 (grid 768/half).
// QUAD-MAJOR pixels. T16-tiled output; 8-t register acc, direct sector
// stores (2 x float4 per 8-t group). No staging LDS.
// ---------------------------------------------------------------------------
template<int H>
__global__ __launch_bounds__(576) void k_wsum1(const uint2* __restrict__ xb,
                                               const float* __restrict__ w1,
                                               float* __restrict__ ws) {
    __shared__ float wsh[100];
    __shared__ float tbl[10550];
    int tid = threadIdx.x;
    int tch = blockIdx.x & 3;
    int img = blockIdx.x >> 2;            // 0..191
    int b = img >> 2, oc4 = img & 3;
    int oc = H * 4 + oc4;
    if (tid < 100) wsh[tid] = w1[oc * 100 + tid];
    __syncthreads();
    for (int e = tid; e < 10240; e += 576) {
        int pr = e / 5120;
        int ky = (e / 1024) % 5;
        int i = e & 1023;
        int lo = i & 31, hi = i >> 5;
        float val = 0.f;
#pragma unroll
        for (int k = 0; k < 5; ++k)
            val += ((lo >> k) & 1) ? wsh[pr * 50 + ky * 5 + k] : 0.f;
#pragma unroll
        for (int k = 0; k < 5; ++k)
            val += ((hi >> k) & 1) ? wsh[pr * 50 + 25 + ky * 5 + k] : 0.f;
        tbl[(pr * 5 + ky) * 1055 + lo + 33 * hi] = val;
    }
    __syncthreads();
    int q = tid >> 2, s = tid & 3;
    int ox = (q % 12) * 2 + (s & 1);
    int oy = (q / 12) * 2 + (s >> 1);
    float* op = ws + (size_t)((b * 4 + oc4) * 576 + tid) * 16;
    for (int sub = 0; sub < 4; ++sub) {
        int t0 = tch * 32 + sub * 8;
        float acc[8];
#pragma unroll
        for (int j = 0; j < 8; ++j) {
            int t = t0 + j;
            const uint2* rp = xb + ((size_t)t * 48 + b) * 56 + oy;
            float a = 0.f;
#pragma unroll
            for (int ky = 0; ky < 5; ++ky) {
                uint2 r0 = rp[ky];
                uint2 r1 = rp[28 + ky];
                a += tbl[ky * 1055 + (int)(((r0.x >> ox) & 31u) + 33u * ((r0.y >> ox) & 31u))];
                a += tbl[5275 + ky * 1055 + (int)(((r1.x >> ox) & 31u) + 33u * ((r1.y >> ox) & 31u))];
            }
            acc[j] = a;
        }
        float* wp = op + (size_t)(t0 >> 4) * 1769472 + (t0 & 15);
        *(float4*)(wp)     = make_float4(acc[0], acc[1], acc[2], acc[3]);
        *(float4*)(wp + 4) = make_float4(acc[4], acc[5], acc[6], acc[7]);
    }
}

// ---------------------------------------------------------------------------
// k_scan1: conv1 LIF + pool1 LIF, oc half H. Wave = 64 neurons = 16 quads.
// T16-tiled reads. Staging st1[(H*1728 + wave)*128 + t]. 1728 waves/half.
// ---------------------------------------------------------------------------
template<int H>
__global__ __launch_bounds__(256) void k_scan1(const float* __restrict__ ws,
                                               unsigned short* __restrict__ st1) {
    int wv = blockIdx.x * 4 + (threadIdx.x >> 6);   // 0..1727
    int lane = threadIdx.x & 63;
    const float* bp = ws + (size_t)(wv * 64 + lane) * 16;
    unsigned short* so = st1 + ((size_t)(H * 1728 + wv)) * 128;
    float u = 0.f, v = 0.f, rf = 0.f;
    float pu = 0.f, pv = 0.f, prf = 0.f;
    float sp = 0.f;
    unsigned int mb[4];
    float4 cur[4], nxt[4];
#pragma unroll
    for (int i = 0; i < 4; ++i) cur[i] = *(const float4*)(bp + i * 4);
    for (int tb = 0; tb < 8; ++tb) {
        if (tb < 7) {
            const float* np = bp + (size_t)(tb + 1) * 1769472;
#pragma unroll
            for (int i = 0; i < 4; ++i) nxt[i] = *(const float4*)(np + i * 4);
        }
#pragma unroll
        for (int j = 0; j < 16; ++j) {
            int t = tb * 16 + j;
            float w = f4_elem(cur[j >> 2], j & 3);
            float cnt = dpp_add_xor2(dpp_add_xor1(sp));
            float ps = dyn_step(88.0f * cnt, pu, pv, prf);
            unsigned long long bal = __ballot(((lane & 3) == 0) && (ps > 0.5f));
            unsigned int m = compress4(bal);
            int sl = (t >> 1) & 3;
            mb[sl] = (t & 1) ? (mb[sl] | (m << 16)) : m;
            if ((t & 7) == 7 && lane == 0)
                *(uint4*)(so + (t & ~7)) = make_uint4(mb[0], mb[1], mb[2], mb[3]);
            sp = dyn_step(w, u, v, rf);
        }
        if (tb < 7) {
#pragma unroll
            for (int i = 0; i < 4; ++i) cur[i] = nxt[i];
        }
    }
}

// k_mb1: st1 -> pb16 row masks [t][b][y+1][oc] (12 bits << 1). 589824 thr.
__global__ __launch_bounds__(256) void k_mb1(const unsigned short* __restrict__ st1,
                                             unsigned short* __restrict__ pb16) {
    int gid = blockIdx.x * 256 + threadIdx.x;
    int oc = gid & 7; int r = gid >> 3;
    int y = r % 12; r /= 12;
    int b = r % 48; int t = r / 48;
    int base = (oc >> 2) * 1728 + (b * 4 + (oc & 3)) * 9;
    int Q0 = y * 12;
    int w0 = Q0 >> 4, off = Q0 & 15;
    unsigned int v0 = st1[(size_t)(base + w0) * 128 + t];
    unsigned int v1 = (off > 4) ? (unsigned int)st1[(size_t)(base + w0 + 1) * 128 + t] : 0u;
    unsigned int m = ((v0 >> off) | (v1 << (16 - off))) & 0xFFFu;
    pb16[((size_t)(t * 48 + b) * 14 + y + 1) * 8 + oc] = (unsigned short)(m << 1);
}

// ---------------------------------------------------------------------------
// k_wsum2: conv2 wsum (8->16ch, 3x3, 12->12). LUT 6-bit windows at lo+9*hi.
// QUAD-MAJOR pixels. T16-tiled output, register acc + sector stores.
// ---------------------------------------------------------------------------
__global__ __launch_bounds__(576) void k_wsum2(const unsigned short* __restrict__ pb16,
                                               const float* __restrict__ w2,
                                               float* __restrict__ ws) {
    __shared__ float wsh[288];
    __shared__ float tbl[3408];
    int tid = threadIdx.x;
    int tch = blockIdx.x & 3;
    int g = blockIdx.x >> 2;              // 0..191
    if (tid < 288) {
        int oc = (g * 4 + tid / 72) & 15;
        wsh[tid] = w2[oc * 72 + (tid % 72)];
    }
    __syncthreads();
    for (int e = tid; e < 3072; e += 576) {
        int isel = e / 768;
        int pr = (e / 192) % 4;
        int ky = (e / 64) % 3;
        int i = e & 63;
        int lo = i & 7, hi = i >> 3;
        float val = 0.f;
#pragma unroll
        for (int k = 0; k < 3; ++k)
            val += ((lo >> k) & 1) ? wsh[isel * 72 + (2 * pr) * 9 + ky * 3 + k] : 0.f;
#pragma unroll
        for (int k = 0; k < 3; ++k)
            val += ((hi >> k) & 1) ? wsh[isel * 72 + (2 * pr + 1) * 9 + ky * 3 + k] : 0.f;
        tbl[isel * 852 + (pr * 3 + ky) * 71 + lo + 9 * hi] = val;
    }
    __syncthreads();
    int isel = tid / 144;
    int pix = tid % 144;
    int q = pix >> 2, s = pix & 3;
    int ox = (q % 6) * 2 + (s & 1);
    int oy = (q / 6) * 2 + (s >> 1);
    int b = (g * 4 + isel) >> 4;
    const float* tb = tbl + isel * 852;
    float* op = ws + (size_t)(g * 576 + tid) * 16;
    for (int sub = 0; sub < 4; ++sub) {
        int t0 = tch * 32 + sub * 8;
        float acc[8];
#pragma unroll
        for (int j = 0; j < 8; ++j) {
            int t = t0 + j;
            float a = 0.f;
            if (t > 0) {
                const uint4* rp = (const uint4*)(pb16 + (((size_t)(t - 1) * 48 + b) * 14 + oy) * 8);
#pragma unroll
                for (int ky = 0; ky < 3; ++ky) {
                    uint4 row = rp[ky];
                    unsigned int wd[4] = {row.x, row.y, row.z, row.w};
#pragma unroll
                    for (int pr = 0; pr < 4; ++pr) {
                        unsigned int lo = (wd[pr] >> ox) & 7u;
                        unsigned int hi = (wd[pr] >> (16 + ox)) & 7u;
                        a += tb[(pr * 3 + ky) * 71 + (int)(lo + 9u * hi)];
                    }
                }
            }
            acc[j] = a;
        }
        float* wp = op + (size_t)(t0 >> 4) * 1769472 + (t0 & 15);
        *(float4*)(wp)     = make_float4(acc[0], acc[1], acc[2], acc[3]);
        *(float4*)(wp + 4) = make_float4(acc[4], acc[5], acc[6], acc[7]);
    }
}

// ---------------------------------------------------------------------------
// k_scan2: conv2 LIF + pool2 LIF. Block 576 = 4 images (9 waves); wave = 16
// quads. T16-tiled reads. Staging st2[(g4*9 + wloc)*128 + t]. 1728 waves.
// ---------------------------------------------------------------------------
__global__ __launch_bounds__(576) void k_scan2(const float* __restrict__ ws,
                                               unsigned short* __restrict__ st2) {
    int tid = threadIdx.x;
    int wloc = tid >> 6, lane = tid & 63;
    int g4 = blockIdx.x;                  // 0..191
    const float* bp = ws + (size_t)(g4 * 576 + tid) * 16;
    unsigned short* so = st2 + ((size_t)(g4 * 9 + wloc)) * 128;
    float u = 0.f, v = 0.f, rf = 0.f;
    float pu = 0.f, pv = 0.f, prf = 0.f;
    float sp = 0.f;
    unsigned int mb[4];
    float4 cur[4], nxt[4];
#pragma unroll
    for (int i = 0; i < 4; ++i) cur[i] = *(const float4*)(bp + i * 4);
    for (int tb = 0; tb < 8; ++tb) {
        if (tb < 7) {
            const float* np = bp + (size_t)(tb + 1) * 1769472;
#pragma unroll
            for (int i = 0; i < 4; ++i) nxt[i] = *(const float4*)(np + i * 4);
        }
#pragma unroll
        for (int j = 0; j < 16; ++j) {
            int t = tb * 16 + j;
            float w = f4_elem(cur[j >> 2], j & 3);
            float cnt = dpp_add_xor2(dpp_add_xor1(sp));
            float ps = dyn_step(88.0f * cnt, pu, pv, prf);
            unsigned long long bal = __ballot(((lane & 3) == 0) && (ps > 0.5f));
            unsigned int m = compress4(bal);
            int sl = (t >> 1) & 3;
            mb[sl] = (t & 1) ? (mb[sl] | (m << 16)) : m;
            if ((t & 7) == 7 && lane == 0)
                *(uint4*)(so + (t & ~7)) = make_uint4(mb[0], mb[1], mb[2], mb[3]);
            sp = dyn_step(w, u, v, rf);
        }
        if (tb < 7) {
#pragma unroll
            for (int i = 0; i < 4; ++i) cur[i] = nxt[i];
        }
    }
}

// k_mb2: st2 -> pb2 row masks [t][b][y+1][oc] (6 bits << 1). 589824 thr.
__global__ __launch_bounds__(256) void k_mb2(const unsigned short* __restrict__ st2,
                                             unsigned short* __restrict__ pb2) {
    int gid = blockIdx.x * 256 + threadIdx.x;
    int oc = gid & 15; int r = gid >> 4;
    int y = r % 6; r /= 6;
    int b = r % 48; int t = r / 48;
    int img = b * 16 + oc;
    int g4 = img >> 2, lI = img & 3;
    int Q0 = lI * 36 + y * 6;
    int w0 = Q0 >> 4, off = Q0 & 15;
    unsigned int v0 = st2[(size_t)(g4 * 9 + w0) * 128 + t];
    unsigned int v1 = (off > 10) ? (unsigned int)st2[(size_t)(g4 * 9 + w0 + 1) * 128 + t] : 0u;
    unsigned int m = ((v0 >> off) | (v1 << (16 - off))) & 0x3Fu;
    pb2[((size_t)(t * 48 + b) * 8 + y + 1) * 16 + oc] = (unsigned short)(m << 1);
}

// ---------------------------------------------------------------------------
// k_wsum3: conv3 wsum (16->32ch, 3x3, 6->6). QUAD-MAJOR. t-chunk 16 (grid
// 768). T16-tiled output (tile = tch), register acc + sector stores.
// ---------------------------------------------------------------------------
__global__ __launch_bounds__(576) void k_wsum3(const unsigned short* __restrict__ pb2,
                                               const float* __restrict__ w3,
                                               float* __restrict__ ws) {
    __shared__ float wsh[576];
    __shared__ float tbl[6816];
    int tid = threadIdx.x;
    int tch = blockIdx.x & 7;
    int gb = blockIdx.x >> 3;             // 0..95 = ocg*12 + bg
    int ocg = gb / 12, bg = gb % 12;
    {
        int oc_t = ocg * 4 + tid / 144;
        wsh[tid] = w3[oc_t * 144 + (tid % 144)];
    }
    __syncthreads();
    for (int e = tid; e < 6144; e += 576) {
        int osel = e / 1536;
        int pr = (e / 192) % 8;
        int ky = (e / 64) % 3;
        int i = e & 63;
        int lo = i & 7, hi = i >> 3;
        float val = 0.f;
#pragma unroll
        for (int k = 0; k < 3; ++k)
            val += ((lo >> k) & 1) ? wsh[osel * 144 + (2 * pr) * 9 + ky * 3 + k] : 0.f;
#pragma unroll
        for (int k = 0; k < 3; ++k)
            val += ((hi >> k) & 1) ? wsh[osel * 144 + (2 * pr + 1) * 9 + ky * 3 + k] : 0.f;
        tbl[osel * 1704 + (pr * 3 + ky) * 71 + lo + 9 * hi] = val;
    }
    __syncthreads();
    int osel = tid / 144;
    int rem = tid % 144;
    int bsel = rem / 36;
    int pix = rem % 36;
    int q = pix >> 2, s = pix & 3;
    int ox = (q % 3) * 2 + (s & 1);
    int oy = (q / 3) * 2 + (s >> 1);
    int oc = ocg * 4 + osel;
    int b = bg * 4 + bsel;
    const float* tb = tbl + osel * 1704;
    float* op = ws + (size_t)tch * 884736 + (size_t)((b * 32 + oc) * 36 + pix) * 16;
    for (int sub = 0; sub < 2; ++sub) {
        int t0 = tch * 16 + sub * 8;
        float acc[8];
#pragma unroll
        for (int j = 0; j < 8; ++j) {
            int t = t0 + j;
            float a = 0.f;
            if (t > 0) {
                const uint4* rp = (const uint4*)(pb2 + (((size_t)(t - 1) * 48 + b) * 8 + oy) * 16);
#pragma unroll
                for (int ky = 0; ky < 3; ++ky) {
                    uint4 rA = rp[ky * 2];
                    uint4 rB = rp[ky * 2 + 1];
                    unsigned int wd[8] = {rA.x, rA.y, rA.z, rA.w, rB.x, rB.y, rB.z, rB.w};
#pragma unroll
                    for (int pr = 0; pr < 8; ++pr) {
                        unsigned int lo = (wd[pr] >> ox) & 7u;
                        unsigned int hi = (wd[pr] >> (16 + ox)) & 7u;
                        a += tb[(pr * 3 + ky) * 71 + (int)(lo + 9u * hi)];
                    }
                }
            }
            acc[j] = a;
        }
        float* wp = op + sub * 8;
        *(float4*)(wp)     = make_float4(acc[0], acc[1], acc[2], acc[3]);
        *(float4*)(wp + 4) = make_float4(acc[4], acc[5], acc[6], acc[7]);
    }
}

// ---------------------------------------------------------------------------
// k_scan3: conv3 LIF + pool3 LIF. 864 waves; T16-tiled reads; staging
// st3[wave*128 + t].
// ---------------------------------------------------------------------------
__global__ __launch_bounds__(256) void k_scan3(const float* __restrict__ ws,
                                               unsigned short* __restrict__ st3) {
    int wv = blockIdx.x * 4 + (threadIdx.x >> 6);   // 0..863
    int lane = threadIdx.x & 63;
    const float* bp = ws + (size_t)(wv * 64 + lane) * 16;
    unsigned short* so = st3 + (size_t)wv * 128;
    float u = 0.f, v = 0.f, rf = 0.f;
    float pu = 0.f, pv = 0.f, prf = 0.f;
    float sp = 0.f;
    unsigned int mb[4];
    float4 cur[4], nxt[4];
#pragma unroll
    for (int i = 0; i < 4; ++i) cur[i] = *(const float4*)(bp + i * 4);
    for (int tb = 0; tb < 8; ++tb) {
        if (tb < 7) {
            const float* np = bp + (size_t)(tb + 1) * 884736;
#pragma unroll
            for (int i = 0; i < 4; ++i) nxt[i] = *(const float4*)(np + i * 4);
        }
#pragma unroll
        for (int j = 0; j < 16; ++j) {
            int t = tb * 16 + j;
            float w = f4_elem(cur[j >> 2], j & 3);
            float cnt = dpp_add_xor2(dpp_add_xor1(sp));
            float ps = dyn_step(88.0f * cnt, pu, pv, prf);
            unsigned long long bal = __ballot(((lane & 3) == 0) && (ps > 0.5f));
            unsigned int m = compress4(bal);
            int sl = (t >> 1) & 3;
            mb[sl] = (t & 1) ? (mb[sl] | (m << 16)) : m;
            if ((t & 7) == 7 && lane == 0)
                *(uint4*)(so + (t & ~7)) = make_uint4(mb[0], mb[1], mb[2], mb[3]);
            sp = dyn_step(w, u, v, rf);
        }
        if (tb < 7) {
#pragma unroll
            for (int i = 0; i < 4; ++i) cur[i] = nxt[i];
        }
    }
}

// k_mb3: st3 -> bf16 A-matrix a3[(t+1)*13824 + G] (delay-shift folded).
__global__ __launch_bounds__(256) void k_mb3(const unsigned short* __restrict__ st3,
                                             unsigned short* __restrict__ a3) {
    int gid = blockIdx.x * 256 + threadIdx.x;
    if (gid >= 1755648) return;
    int G = gid % 13824, t = gid / 13824;
    unsigned int bit = ((unsigned int)st3[(size_t)(G >> 4) * 128 + t] >> (G & 15)) & 1u;
    a3[(size_t)(t + 1) * 13824 + G] = bit ? 0x3F80 : 0;
}

// ---------------------------------------------------------------------------
// k_wsplit: wfc1[512][288] f32 -> wb[3][288][512] bf16 (bf16x3 split).
// ---------------------------------------------------------------------------
__global__ __launch_bounds__(256) void k_wsplit(const float* __restrict__ wfc1,
                                                unsigned short* __restrict__ wb) {
    int gid = blockIdx.x * 256 + threadIdx.x;
    int o = gid / 288, k = gid % 288;
    float w = wfc1[gid];
    unsigned short b0 = f2bf(w);
    float r1 = w - bf2f(b0);
    unsigned short b1 = f2bf(r1);
    float r2 = r1 - bf2f(b1);
    unsigned short b2 = f2bf(r2);
    wb[(size_t)k * 512 + o] = b0;
    wb[(size_t)147456 + k * 512 + o] = b1;
    wb[(size_t)294912 + k * 512 + o] = b2;
}

// ---------------------------------------------------------------------------
// k_fc1mm: wsf1[m][o] = A x W via mfma_f32_16x16x32_bf16. Linear coalesced
// epilogue (wsf1[m*512+n]).
// ---------------------------------------------------------------------------
__global__ __launch_bounds__(256) void k_fc1mm(const unsigned short* __restrict__ a3,
                                               const unsigned short* __restrict__ wb,
                                               float* __restrict__ wsf1) {
    __shared__ unsigned short Bs[16 * 872];
    int tid = threadIdx.x;
    int nt = blockIdx.x & 31;
    int mc = blockIdx.x >> 5;
    int n0 = nt * 16;
    for (int idx = tid; idx < 13824; idx += 256) {
        int kp = idx >> 4;
        int n = idx & 15;
        Bs[n * 872 + kp] = wb[(size_t)kp * 512 + n0 + n];
    }
    __syncthreads();
    int wave = tid >> 6;
    int lane = tid & 63;
    int ln = lane & 15, quad = lane >> 4;
#pragma unroll
    for (int i = 0; i < 4; ++i) {
        int m0 = (mc * 16 + wave * 4 + i) * 16;
        const unsigned short* arow = a3 + (size_t)(m0 + ln) * 288 + quad * 8;
        ffrag acc = {0.f, 0.f, 0.f, 0.f};
#pragma unroll
        for (int kb = 0; kb < 9; ++kb) {
            bfrag av = *(const bfrag*)(arow + kb * 32);
#pragma unroll
            for (int c = 0; c < 3; ++c) {
                bfrag bv = *(const bfrag*)(&Bs[ln * 872 + c * 288 + kb * 32 + quad * 8]);
                acc = __builtin_amdgcn_mfma_f32_16x16x32_bf16(av, bv, acc, 0, 0, 0);
            }
        }
        float* wout = wsf1 + (size_t)(m0 + quad * 4) * 512 + n0 + ln;
        wout[0] = acc[0];
        wout[512] = acc[1];
        wout[1024] = acc[2];
        wout[1536] = acc[3];
    }
}

// k_fc1s: fc1 LIF scan, linear strided reads + 16-deep prefetch.
__global__ __launch_bounds__(256) void k_fc1s(const float* __restrict__ wsf1,
                                              float* __restrict__ f1f) {
    int tid = blockIdx.x * 256 + threadIdx.x;   // 0..24575
    float u = 0.f, v = 0.f, rf = 0.f;
    float wbuf[16];
#pragma unroll
    for (int i = 0; i < 16; ++i) wbuf[i] = wsf1[(size_t)i * 24576 + tid];
    for (int tb = 0; tb < 128; tb += 16) {
#pragma unroll
        for (int j = 0; j < 16; ++j) {
            int t = tb + j;
            float w = wbuf[j];
            if (t + 16 < 128) wbuf[j] = wsf1[(size_t)(t + 16) * 24576 + tid];
            float s = dyn_step(w, u, v, rf);
            f1f[(size_t)t * 24576 + tid] = s;
        }
    }
}

// k_fc2w: fc2 wsum, parallel over t. Wave per (t,b).
__global__ __launch_bounds__(256) void k_fc2w(const float* __restrict__ f1f,
                                              const float* __restrict__ wfc2,
                                              float* __restrict__ wsf2) {
    int wv = blockIdx.x * 4 + (threadIdx.x >> 6);   // 0..6143
    int lane = threadIdx.x & 63;
    int b = wv % 48, t = wv / 48;
    int o = lane & 1, kq = lane >> 1;
    float acc = 0.f;
    if (t > 0) {
        const float* wp = wfc2 + o * 512 + kq * 16;
        const float* sp = f1f + (size_t)(t - 1) * 24576 + b * 512 + kq * 16;
#pragma unroll
        for (int i = 0; i < 16; ++i) acc += wp[i] * sp[i];
    }
#pragma unroll
    for (int m = 2; m < 64; m <<= 1) acc += __shfl_xor(acc, m, 64);
    if (lane < 2) wsf2[(size_t)t * 96 + b * 2 + o] = acc;
}

// k_fc2s: fc2 LIF scan + delay-shift into out [B,2,T]. 96 active threads.
__global__ __launch_bounds__(128) void k_fc2s(const float* __restrict__ wsf2,
                                              float* __restrict__ out) {
    int tid = threadIdx.x;
    if (tid >= 96) return;
    float* ob = out + tid * 128;       // tid = b*2+o
    ob[0] = 0.0f;
    float u = 0.f, v = 0.f, rf = 0.f;
    float wbuf[8];
#pragma unroll
    for (int i = 0; i < 8; ++i) wbuf[i] = wsf2[(size_t)i * 96 + tid];
    for (int tb = 0; tb < 128; tb += 8) {
#pragma unroll
        for (int j = 0; j < 8; ++j) {
            int t = tb + j;
            float w = wbuf[j];
            if (t + 8 < 128) wbuf[j] = wsf2[(size_t)(t + 8) * 96 + tid];
            float s = dyn_step(w, u, v, rf);
            if (t < 127) ob[t + 1] = s;
        }
    }
}

// ---------------------------------------------------------------------------
extern "C" void kernel_launch(void* const* d_in, const int* in_sizes, int n_in,
                              void* d_out, int out_size, void* d_ws, size_t ws_size,
                              hipStream_t stream) {
    const float* in   = (const float*)d_in[0];
    const float* w1   = (const float*)d_in[1];
    const float* w2   = (const float*)d_in[2];
    const float* w3   = (const float*)d_in[3];
    const float* wfc1 = (const float*)d_in[4];
    const float* wfc2 = (const float*)d_in[5];
    float* out = (float*)d_out;
    char* ws = (char*)d_ws;

    float*          slab = (float*)(ws);                       // 56,623,104 (conv wsums; wsf1 reuse)
    uint2*          xb   = (uint2*)(ws + 56623104);            //  2,752,512
    unsigned short* pb16 = (unsigned short*)(ws + 59375616);   //  1,376,256
    unsigned short* pb2  = (unsigned short*)(ws + 60751872);   //  1,572,864
    float*          f1f  = (float*)(ws + 64094208);            // 12,582,912
    unsigned short* a3   = (unsigned short*)(ws + 76677120);   //  3,538,944 [6144][288] bf16
    unsigned short* wb   = (unsigned short*)(ws + 80216064);   //    884,736 [3][288][512] bf16
    unsigned short* st1  = (unsigned short*)(ws + 81100800);   //    884,736 [3456 waves][128] u16
    unsigned short* st2  = (unsigned short*)(ws + 81985536);   //    442,368 [1728 waves][128] u16
    unsigned short* st3  = (unsigned short*)(ws + 82427904);   //    221,184 [864 waves][128] u16
    float*          wsf1 = (float*)(ws);                       // 12,582,912 (slab reuse, post-scan3)
    float*          wsf2 = (float*)(ws + 16777216);            //     49,152 (slab reuse, disjoint)
    // total 82,649,088 bytes

    hipMemsetAsync(xb, 0, 2752512, stream);     // pad rows 0/27
    hipMemsetAsync(pb16, 0, 1376256, stream);   // pad rows 0/13
    hipMemsetAsync(pb2, 0, 1572864, stream);    // pad rows 0/7
    hipMemsetAsync(a3, 0, 27648, stream);       // A rows t=0 (48*288 bf16)

    k_wsplit  <<<576, 256, 0, stream>>>(wfc1, wb);
    k_masks   <<<624, 256, 0, stream>>>(in, xb);
    k_wsum1<0><<<768, 576, 0, stream>>>(xb, w1, slab);
    k_scan1<0><<<432, 256, 0, stream>>>(slab, st1);
    k_wsum1<1><<<768, 576, 0, stream>>>(xb, w1, slab);
    k_scan1<1><<<432, 256, 0, stream>>>(slab, st1);
    k_mb1     <<<2304, 256, 0, stream>>>(st1, pb16);
    k_wsum2   <<<768, 576, 0, stream>>>(pb16, w2, slab);
    k_scan2   <<<192, 576, 0, stream>>>(slab, st2);
    k_mb2     <<<2304, 256, 0, stream>>>(st2, pb2);
    k_wsum3   <<<768, 576, 0, stream>>>(pb2, w3, slab);
    k_scan3   <<<216, 256, 0, stream>>>(slab, st3);
    k_mb3     <<<6858, 256, 0, stream>>>(st3, a3);
    k_fc1mm   <<<768, 256, 0, stream>>>(a3, wb, wsf1);
    k_fc1s    <<<96, 256, 0, stream>>>(wsf1, f1f);
    k_fc2w    <<<1536, 256, 0, stream>>>(f1f, wfc2, wsf2);
    k_fc2s    <<<1, 128, 0, stream>>>(wsf2, out);
}

// Round 14
// 435.326 us; speedup vs baseline: 1.1690x; 1.1690x over previous
//
#include <hip/hip_runtime.h>

// ---------------------------------------------------------------------------
// SNN forward, split-phase v5.3.
// wsum (parallel over t, LDS-LUT conv / MFMA fc) + scan (serial LIF).
// T16-tiled wsum slabs, sector-perfect register stores.
// v5.3: conv1 LUT vectorized across oc — single-channel 5-bit windows index
// float4 entries covering the 4-oc quad (one thread computes 4 oc; window
// loads/extractions amortized 4x; LDS table 42->10.6 KB). Round-13 PMC:
// wsum1 was issue/redundancy-bound, not LDS-capacity-bound.
// ---------------------------------------------------------------------------

#define THETA 5120.0f

typedef __attribute__((ext_vector_type(8))) short bfrag;   // 8 bf16 (4 VGPRs)
typedef __attribute__((ext_vector_type(4))) float ffrag;   // 4 f32

__device__ __forceinline__ float dyn_step(float x, float& u, float& v, float& r) {
#pragma clang fp contract(off)
    u = 0.75f * u + 64.0f * x;          // current decay (1024/4096), W_SCALE=64
    float vn = 0.96875f * v + u;        // voltage decay (128/4096)
    vn = (r > 0.0f) ? 0.0f : vn;        // refractory clamp
    float s;
    if (vn >= THETA) { s = 1.0f; v = 0.0f; r = 1.0f; }
    else             { s = 0.0f; v = vn; r = fmaxf(r - 1.0f, 0.0f); }
    return s;
}

__device__ __forceinline__ float dpp_add_xor1(float x) {
    int y = __builtin_amdgcn_update_dpp(0, __float_as_int(x), 0xB1, 0xF, 0xF, true);
    return x + __int_as_float(y);
}
__device__ __forceinline__ float dpp_add_xor2(float x) {
    int y = __builtin_amdgcn_update_dpp(0, __float_as_int(x), 0x4E, 0xF, 0xF, true);
    return x + __int_as_float(y);
}

// compress bits at positions 4k (k=0..15) of a 64-bit word into 16 bits
__device__ __forceinline__ unsigned int compress4(unsigned long long x) {
    x &= 0x1111111111111111ull;
    x = (x | (x >> 3))  & 0x0303030303030303ull;
    x = (x | (x >> 6))  & 0x000F000F000F000Full;
    x = (x | (x >> 12)) & 0x000000FF000000FFull;
    x = (x | (x >> 24)) & 0xFFFFull;
    return (unsigned int)x;
}

__device__ __forceinline__ unsigned short f2bf(float f) {
    unsigned int u = __float_as_uint(f);
    unsigned int r = (u + 0x7FFFu + ((u >> 16) & 1u)) >> 16;   // RNE
    return (unsigned short)r;
}
__device__ __forceinline__ float bf2f(unsigned short b) {
    return __uint_as_float(((unsigned int)b) << 16);
}

__device__ __forceinline__ float f4_elem(float4 v, int j) {
    return (j == 0) ? v.x : (j == 1) ? v.y : (j == 2) ? v.z : v.w;
}

// ---------------------------------------------------------------------------
// k_masks: in [B=48,C=4,26,26,T=128] f32 -> xb uint2[t][b][pr][28 rows]
// ---------------------------------------------------------------------------
__global__ __launch_bounds__(256) void k_masks(const float* __restrict__ in,
                                               uint2* __restrict__ xb) {
    int wv = blockIdx.x * 4 + (threadIdx.x >> 6);
    int lane = threadIdx.x & 63;
    int y = wv % 26; int r = wv / 26;
    int pr = r & 1; int b = r >> 1;
    int ch = lane >> 5;
    int x = lane & 31;
    int act = x < 26;
    int xc = act ? x : 25;
    const float4* src = (const float4*)(in + (size_t)(((b * 4 + pr * 2 + ch) * 26 + y) * 26 + xc) * 128);
    uint2* dst = xb + ((size_t)b * 2 + pr) * 28 + (y + 1);
    for (int t4 = 0; t4 < 32; ++t4) {
        float4 f = src[t4];
#pragma unroll
        for (int k = 0; k < 4; ++k) {
            float fv = f4_elem(f, k);
            unsigned long long bal = __ballot(act && (fv != 0.0f));
            if (lane == 0) {
                unsigned int lo = ((unsigned int)bal & 0x03FFFFFFu) << 1;
                unsigned int hi = ((unsigned int)(bal >> 32) & 0x03FFFFFFu) << 1;
                dst[(size_t)(t4 * 4 + k) * 2688] = make_uint2(lo, hi);
            }
        }
    }
}

// ---------------------------------------------------------------------------
// k_wsum1: conv1 wsum (4->8ch, 5x5, 26->24), oc-quad H (oc = H*4..H*4+3).
// Single-channel 5-bit windows -> float4 LUT over the oc quad:
// tbl4[(ch*5+ky)*33 + idx]. Block 576 = one b's pixels (quad-major);
// t-chunk 8 (grid 48*16=768). One thread = one pixel, ALL 4 oc.
// T16-tiled output, 8-t register acc, sector stores.
// ---------------------------------------------------------------------------
template<int H>
__global__ __launch_bounds__(576) void k_wsum1(const uint2* __restrict__ xb,
                                               const float* __restrict__ w1,
                                               float* __restrict__ ws) {
    __shared__ float wsh[400];
    __shared__ ffrag tbl4[660];           // [4ch][5ky][33] float4 (10.6 KB)
    int tid = threadIdx.x;
    int tch = blockIdx.x & 15;
    int b = blockIdx.x >> 4;              // 0..47
    if (tid < 400) wsh[tid] = w1[H * 400 + tid];   // [oc4][ch][5][5]
    __syncthreads();
    for (int e = tid; e < 660; e += 576) {
        int ch = e / 165;
        int rem = e % 165;
        int ky = rem / 33;
        int idx = rem % 33;
        ffrag val = {0.f, 0.f, 0.f, 0.f};
#pragma unroll
        for (int oc4 = 0; oc4 < 4; ++oc4) {
            float a = 0.f;
#pragma unroll
            for (int k = 0; k < 5; ++k)
                a += ((idx >> k) & 1) ? wsh[oc4 * 100 + ch * 25 + ky * 5 + k] : 0.f;
            val[oc4] = a;
        }
        tbl4[(ch * 5 + ky) * 33 + idx] = val;
    }
    __syncthreads();
    int q = tid >> 2, s = tid & 3;
    int ox = (q % 12) * 2 + (s & 1);
    int oy = (q / 12) * 2 + (s >> 1);
    int t0 = tch * 8;
    ffrag acc[8];
#pragma unroll
    for (int j = 0; j < 8; ++j) {
        int t = t0 + j;
        const uint2* rp = xb + ((size_t)t * 48 + b) * 56 + oy;
        ffrag a = {0.f, 0.f, 0.f, 0.f};
#pragma unroll
        for (int ky = 0; ky < 5; ++ky) {
            uint2 r0 = rp[ky];
            uint2 r1 = rp[28 + ky];
            a += tbl4[ky * 33 + (int)((r0.x >> ox) & 31u)];
            a += tbl4[(5 + ky) * 33 + (int)((r0.y >> ox) & 31u)];
            a += tbl4[(10 + ky) * 33 + (int)((r1.x >> ox) & 31u)];
            a += tbl4[(15 + ky) * 33 + (int)((r1.y >> ox) & 31u)];
        }
        acc[j] = a;
    }
    size_t tilebase = (size_t)(t0 >> 4) * 1769472 + (t0 & 15);
#pragma unroll
    for (int oc4 = 0; oc4 < 4; ++oc4) {
        float* wp = ws + tilebase + (size_t)((b * 4 + oc4) * 576 + tid) * 16;
        *(float4*)(wp)     = make_float4(acc[0][oc4], acc[1][oc4], acc[2][oc4], acc[3][oc4]);
        *(float4*)(wp + 4) = make_float4(acc[4][oc4], acc[5][oc4], acc[6][oc4], acc[7][oc4]);
    }
}

// ---------------------------------------------------------------------------
// k_scan1: conv1 LIF + pool1 LIF, oc half H. Wave = 64 neurons = 16 quads.
// T16-tiled reads. Staging st1[(H*1728 + wave)*128 + t]. 1728 waves/half.
// ---------------------------------------------------------------------------
template<int H>
__global__ __launch_bounds__(256) void k_scan1(const float* __restrict__ ws,
                                               unsigned short* __restrict__ st1) {
    int wv = blockIdx.x * 4 + (threadIdx.x >> 6);   // 0..1727
    int lane = threadIdx.x & 63;
    const float* bp = ws + (size_t)(wv * 64 + lane) * 16;
    unsigned short* so = st1 + ((size_t)(H * 1728 + wv)) * 128;
    float u = 0.f, v = 0.f, rf = 0.f;
    float pu = 0.f, pv = 0.f, prf = 0.f;
    float sp = 0.f;
    unsigned int mb[4];
    float4 cur[4], nxt[4];
#pragma unroll
    for (int i = 0; i < 4; ++i) cur[i] = *(const float4*)(bp + i * 4);
    for (int tb = 0; tb < 8; ++tb) {
        if (tb < 7) {
            const float* np = bp + (size_t)(tb + 1) * 1769472;
#pragma unroll
            for (int i = 0; i < 4; ++i) nxt[i] = *(const float4*)(np + i * 4);
        }
#pragma unroll
        for (int j = 0; j < 16; ++j) {
            int t = tb * 16 + j;
            float w = f4_elem(cur[j >> 2], j & 3);
            float cnt = dpp_add_xor2(dpp_add_xor1(sp));
            float ps = dyn_step(88.0f * cnt, pu, pv, prf);
            unsigned long long bal = __ballot(((lane & 3) == 0) && (ps > 0.5f));
            unsigned int m = compress4(bal);
            int sl = (t >> 1) & 3;
            mb[sl] = (t & 1) ? (mb[sl] | (m << 16)) : m;
            if ((t & 7) == 7 && lane == 0)
                *(uint4*)(so + (t & ~7)) = make_uint4(mb[0], mb[1], mb[2], mb[3]);
            sp = dyn_step(w, u, v, rf);
        }
        if (tb < 7) {
#pragma unroll
            for (int i = 0; i < 4; ++i) cur[i] = nxt[i];
        }
    }
}

// k_mb1: st1 -> pb16 row masks [t][b][y+1][oc] (12 bits << 1). 589824 thr.
__global__ __launch_bounds__(256) void k_mb1(const unsigned short* __restrict__ st1,
                                             unsigned short* __restrict__ pb16) {
    int gid = blockIdx.x * 256 + threadIdx.x;
    int oc = gid & 7; int r = gid >> 3;
    int y = r % 12; r /= 12;
    int b = r % 48; int t = r / 48;
    int base = (oc >> 2) * 1728 + (b * 4 + (oc & 3)) * 9;
    int Q0 = y * 12;
    int w0 = Q0 >> 4, off = Q0 & 15;
    unsigned int v0 = st1[(size_t)(base + w0) * 128 + t];
    unsigned int v1 = (off > 4) ? (unsigned int)st1[(size_t)(base + w0 + 1) * 128 + t] : 0u;
    unsigned int m = ((v0 >> off) | (v1 << (16 - off))) & 0xFFFu;
    pb16[((size_t)(t * 48 + b) * 14 + y + 1) * 8 + oc] = (unsigned short)(m << 1);
}

// ---------------------------------------------------------------------------
// k_wsum2: conv2 wsum (8->16ch, 3x3, 12->12). LUT 6-bit windows at lo+9*hi.
// QUAD-MAJOR pixels. T16-tiled output, register acc + sector stores.
// ---------------------------------------------------------------------------
__global__ __launch_bounds__(576) void k_wsum2(const unsigned short* __restrict__ pb16,
                                               const float* __restrict__ w2,
                                               float* __restrict__ ws) {
    __shared__ float wsh[288];
    __shared__ float tbl[3408];
    int tid = threadIdx.x;
    int tch = blockIdx.x & 3;
    int g = blockIdx.x >> 2;              // 0..191
    if (tid < 288) {
        int oc = (g * 4 + tid / 72) & 15;
        wsh[tid] = w2[oc * 72 + (tid % 72)];
    }
    __syncthreads();
    for (int e = tid; e < 3072; e += 576) {
        int isel = e / 768;
        int pr = (e / 192) % 4;
        int ky = (e / 64) % 3;
        int i = e & 63;
        int lo = i & 7, hi = i >> 3;
        float val = 0.f;
#pragma unroll
        for (int k = 0; k < 3; ++k)
            val += ((lo >> k) & 1) ? wsh[isel * 72 + (2 * pr) * 9 + ky * 3 + k] : 0.f;
#pragma unroll
        for (int k = 0; k < 3; ++k)
            val += ((hi >> k) & 1) ? wsh[isel * 72 + (2 * pr + 1) * 9 + ky * 3 + k] : 0.f;
        tbl[isel * 852 + (pr * 3 + ky) * 71 + lo + 9 * hi] = val;
    }
    __syncthreads();
    int isel = tid / 144;
    int pix = tid % 144;
    int q = pix >> 2, s = pix & 3;
    int ox = (q % 6) * 2 + (s & 1);
    int oy = (q / 6) * 2 + (s >> 1);
    int b = (g * 4 + isel) >> 4;
    const float* tb = tbl + isel * 852;
    float* op = ws + (size_t)(g * 576 + tid) * 16;
    for (int sub = 0; sub < 4; ++sub) {
        int t0 = tch * 32 + sub * 8;
        float acc[8];
#pragma unroll
        for (int j = 0; j < 8; ++j) {
            int t = t0 + j;
            float a = 0.f;
            if (t > 0) {
                const uint4* rp = (const uint4*)(pb16 + (((size_t)(t - 1) * 48 + b) * 14 + oy) * 8);
#pragma unroll
                for (int ky = 0; ky < 3; ++ky) {
                    uint4 row = rp[ky];
                    unsigned int wd[4] = {row.x, row.y, row.z, row.w};
#pragma unroll
                    for (int pr = 0; pr < 4; ++pr) {
                        unsigned int lo = (wd[pr] >> ox) & 7u;
                        unsigned int hi = (wd[pr] >> (16 + ox)) & 7u;
                        a += tb[(pr * 3 + ky) * 71 + (int)(lo + 9u * hi)];
                    }
                }
            }
            acc[j] = a;
        }
        float* wp = op + (size_t)(t0 >> 4) * 1769472 + (t0 & 15);
        *(float4*)(wp)     = make_float4(acc[0], acc[1], acc[2], acc[3]);
        *(float4*)(wp + 4) = make_float4(acc[4], acc[5], acc[6], acc[7]);
    }
}

// ---------------------------------------------------------------------------
// k_scan2: conv2 LIF + pool2 LIF. Block 576 = 4 images (9 waves); wave = 16
// quads. T16-tiled reads. Staging st2[(g4*9 + wloc)*128 + t]. 1728 waves.
// ---------------------------------------------------------------------------
__global__ __launch_bounds__(576) void k_scan2(const float* __restrict__ ws,
                                               unsigned short* __restrict__ st2) {
    int tid = threadIdx.x;
    int wloc = tid >> 6, lane = tid & 63;
    int g4 = blockIdx.x;                  // 0..191
    const float* bp = ws + (size_t)(g4 * 576 + tid) * 16;
    unsigned short* so = st2 + ((size_t)(g4 * 9 + wloc)) * 128;
    float u = 0.f, v = 0.f, rf = 0.f;
    float pu = 0.f, pv = 0.f, prf = 0.f;
    float sp = 0.f;
    unsigned int mb[4];
    float4 cur[4], nxt[4];
#pragma unroll
    for (int i = 0; i < 4; ++i) cur[i] = *(const float4*)(bp + i * 4);
    for (int tb = 0; tb < 8; ++tb) {
        if (tb < 7) {
            const float* np = bp + (size_t)(tb + 1) * 1769472;
#pragma unroll
            for (int i = 0; i < 4; ++i) nxt[i] = *(const float4*)(np + i * 4);
        }
#pragma unroll
        for (int j = 0; j < 16; ++j) {
            int t = tb * 16 + j;
            float w = f4_elem(cur[j >> 2], j & 3);
            float cnt = dpp_add_xor2(dpp_add_xor1(sp));
            float ps = dyn_step(88.0f * cnt, pu, pv, prf);
            unsigned long long bal = __ballot(((lane & 3) == 0) && (ps > 0.5f));
            unsigned int m = compress4(bal);
            int sl = (t >> 1) & 3;
            mb[sl] = (t & 1) ? (mb[sl] | (m << 16)) : m;
            if ((t & 7) == 7 && lane == 0)
                *(uint4*)(so + (t & ~7)) = make_uint4(mb[0], mb[1], mb[2], mb[3]);
            sp = dyn_step(w, u, v, rf);
        }
        if (tb < 7) {
#pragma unroll
            for (int i = 0; i < 4; ++i) cur[i] = nxt[i];
        }
    }
}

// k_mb2: st2 -> pb2 row masks [t][b][y+1][oc] (6 bits << 1). 589824 thr.
__global__ __launch_bounds__(256) void k_mb2(const unsigned short* __restrict__ st2,
                                             unsigned short* __restrict__ pb2) {
    int gid = blockIdx.x * 256 + threadIdx.x;
    int oc = gid & 15; int r = gid >> 4;
    int y = r % 6; r /= 6;
    int b = r % 48; int t = r / 48;
    int img = b * 16 + oc;
    int g4 = img >> 2, lI = img & 3;
    int Q0 = lI * 36 + y * 6;
    int w0 = Q0 >> 4, off = Q0 & 15;
    unsigned int v0 = st2[(size_t)(g4 * 9 + w0) * 128 + t];
    unsigned int v1 = (off > 10) ? (unsigned int)st2[(size_t)(g4 * 9 + w0 + 1) * 128 + t] : 0u;
    unsigned int m = ((v0 >> off) | (v1 << (16 - off))) & 0x3Fu;
    pb2[((size_t)(t * 48 + b) * 8 + y + 1) * 16 + oc] = (unsigned short)(m << 1);
}

// ---------------------------------------------------------------------------
// k_wsum3: conv3 wsum (16->32ch, 3x3, 6->6). QUAD-MAJOR. t-chunk 16 (grid
// 768). T16-tiled output (tile = tch), register acc + sector stores.
// ---------------------------------------------------------------------------
__global__ __launch_bounds__(576) void k_wsum3(const unsigned short* __restrict__ pb2,
                                               const float* __restrict__ w3,
                                               float* __restrict__ ws) {
    __shared__ float wsh[576];
    __shared__ float tbl[6816];
    int tid = threadIdx.x;
    int tch = blockIdx.x & 7;
    int gb = blockIdx.x >> 3;             // 0..95 = ocg*12 + bg
    int ocg = gb / 12, bg = gb % 12;
    {
        int oc_t = ocg * 4 + tid / 144;
        wsh[tid] = w3[oc_t * 144 + (tid % 144)];
    }
    __syncthreads();
    for (int e = tid; e < 6144; e += 576) {
        int osel = e / 1536;
        int pr = (e / 192) % 8;
        int ky = (e / 64) % 3;
        int i = e & 63;
        int lo = i & 7, hi = i >> 3;
        float val = 0.f;
#pragma unroll
        for (int k = 0; k < 3; ++k)
            val += ((lo >> k) & 1) ? wsh[osel * 144 + (2 * pr) * 9 + ky * 3 + k] : 0.f;
#pragma unroll
        for (int k = 0; k < 3; ++k)
            val += ((hi >> k) & 1) ? wsh[osel * 144 + (2 * pr + 1) * 9 + ky * 3 + k] : 0.f;
        tbl[osel * 1704 + (pr * 3 + ky) * 71 + lo + 9 * hi] = val;
    }
    __syncthreads();
    int osel = tid / 144;
    int rem = tid % 144;
    int bsel = rem / 36;
    int pix = rem % 36;
    int q = pix >> 2, s = pix & 3;
    int ox = (q % 3) * 2 + (s & 1);
    int oy = (q / 3) * 2 + (s >> 1);
    int oc = ocg * 4 + osel;
    int b = bg * 4 + bsel;
    const float* tb = tbl + osel * 1704;
    float* op = ws + (size_t)tch * 884736 + (size_t)((b * 32 + oc) * 36 + pix) * 16;
    for (int sub = 0; sub < 2; ++sub) {
        int t0 = tch * 16 + sub * 8;
        float acc[8];
#pragma unroll
        for (int j = 0; j < 8; ++j) {
            int t = t0 + j;
            float a = 0.f;
            if (t > 0) {
                const uint4* rp = (const uint4*)(pb2 + (((size_t)(t - 1) * 48 + b) * 8 + oy) * 16);
#pragma unroll
                for (int ky = 0; ky < 3; ++ky) {
                    uint4 rA = rp[ky * 2];
                    uint4 rB = rp[ky * 2 + 1];
                    unsigned int wd[8] = {rA.x, rA.y, rA.z, rA.w, rB.x, rB.y, rB.z, rB.w};
#pragma unroll
                    for (int pr = 0; pr < 8; ++pr) {
                        unsigned int lo = (wd[pr] >> ox) & 7u;
                        unsigned int hi = (wd[pr] >> (16 + ox)) & 7u;
                        a += tb[(pr * 3 + ky) * 71 + (int)(lo + 9u * hi)];
                    }
                }
            }
            acc[j] = a;
        }
        float* wp = op + sub * 8;
        *(float4*)(wp)     = make_float4(acc[0], acc[1], acc[2], acc[3]);
        *(float4*)(wp + 4) = make_float4(acc[4], acc[5], acc[6], acc[7]);
    }
}

// ---------------------------------------------------------------------------
// k_scan3: conv3 LIF + pool3 LIF. 864 waves; T16-tiled reads; staging
// st3[wave*128 + t].
// ---------------------------------------------------------------------------
__global__ __launch_bounds__(256) void k_scan3(const float* __restrict__ ws,
                                               unsigned short* __restrict__ st3) {
    int wv = blockIdx.x * 4 + (threadIdx.x >> 6);   // 0..863
    int lane = threadIdx.x & 63;
    const float* bp = ws + (size_t)(wv * 64 + lane) * 16;
    unsigned short* so = st3 + (size_t)wv * 128;
    float u = 0.f, v = 0.f, rf = 0.f;
    float pu = 0.f, pv = 0.f, prf = 0.f;
    float sp = 0.f;
    unsigned int mb[4];
    float4 cur[4], nxt[4];
#pragma unroll
    for (int i = 0; i < 4; ++i) cur[i] = *(const float4*)(bp + i * 4);
    for (int tb = 0; tb < 8; ++tb) {
        if (tb < 7) {
            const float* np = bp + (size_t)(tb + 1) * 884736;
#pragma unroll
            for (int i = 0; i < 4; ++i) nxt[i] = *(const float4*)(np + i * 4);
        }
#pragma unroll
        for (int j = 0; j < 16; ++j) {
            int t = tb * 16 + j;
            float w = f4_elem(cur[j >> 2], j & 3);
            float cnt = dpp_add_xor2(dpp_add_xor1(sp));
            float ps = dyn_step(88.0f * cnt, pu, pv, prf);
            unsigned long long bal = __ballot(((lane & 3) == 0) && (ps > 0.5f));
            unsigned int m = compress4(bal);
            int sl = (t >> 1) & 3;
            mb[sl] = (t & 1) ? (mb[sl] | (m << 16)) : m;
            if ((t & 7) == 7 && lane == 0)
                *(uint4*)(so + (t & ~7)) = make_uint4(mb[0], mb[1], mb[2], mb[3]);
            sp = dyn_step(w, u, v, rf);
        }
        if (tb < 7) {
#pragma unroll
            for (int i = 0; i < 4; ++i) cur[i] = nxt[i];
        }
    }
}

// k_mb3: st3 -> bf16 A-matrix a3[(t+1)*13824 + G] (delay-shift folded).
__global__ __launch_bounds__(256) void k_mb3(const unsigned short* __restrict__ st3,
                                             unsigned short* __restrict__ a3) {
    int gid = blockIdx.x * 256 + threadIdx.x;
    if (gid >= 1755648) return;
    int G = gid % 13824, t = gid / 13824;
    unsigned int bit = ((unsigned int)st3[(size_t)(G >> 4) * 128 + t] >> (G & 15)) & 1u;
    a3[(size_t)(t + 1) * 13824 + G] = bit ? 0x3F80 : 0;
}

// ---------------------------------------------------------------------------
// k_wsplit: wfc1[512][288] f32 -> wb[3][288][512] bf16 (bf16x3 split).
// ---------------------------------------------------------------------------
__global__ __launch_bounds__(256) void k_wsplit(const float* __restrict__ wfc1,
                                                unsigned short* __restrict__ wb) {
    int gid = blockIdx.x * 256 + threadIdx.x;
    int o = gid / 288, k = gid % 288;
    float w = wfc1[gid];
    unsigned short b0 = f2bf(w);
    float r1 = w - bf2f(b0);
    unsigned short b1 = f2bf(r1);
    float r2 = r1 - bf2f(b1);
    unsigned short b2 = f2bf(r2);
    wb[(size_t)k * 512 + o] = b0;
    wb[(size_t)147456 + k * 512 + o] = b1;
    wb[(size_t)294912 + k * 512 + o] = b2;
}

// ---------------------------------------------------------------------------
// k_fc1mm: wsf1[m][o] = A x W via mfma_f32_16x16x32_bf16. Linear coalesced
// epilogue (wsf1[m*512+n]).
// ---------------------------------------------------------------------------
__global__ __launch_bounds__(256) void k_fc1mm(const unsigned short* __restrict__ a3,
                                               const unsigned short* __restrict__ wb,
                                               float* __restrict__ wsf1) {
    __shared__ unsigned short Bs[16 * 872];
    int tid = threadIdx.x;
    int nt = blockIdx.x & 31;
    int mc = blockIdx.x >> 5;
    int n0 = nt * 16;
    for (int idx = tid; idx < 13824; idx += 256) {
        int kp = idx >> 4;
        int n = idx & 15;
        Bs[n * 872 + kp] = wb[(size_t)kp * 512 + n0 + n];
    }
    __syncthreads();
    int wave = tid >> 6;
    int lane = tid & 63;
    int ln = lane & 15, quad = lane >> 4;
#pragma unroll
    for (int i = 0; i < 4; ++i) {
        int m0 = (mc * 16 + wave * 4 + i) * 16;
        const unsigned short* arow = a3 + (size_t)(m0 + ln) * 288 + quad * 8;
        ffrag acc = {0.f, 0.f, 0.f, 0.f};
#pragma unroll
        for (int kb = 0; kb < 9; ++kb) {
            bfrag av = *(const bfrag*)(arow + kb * 32);
#pragma unroll
            for (int c = 0; c < 3; ++c) {
                bfrag bv = *(const bfrag*)(&Bs[ln * 872 + c * 288 + kb * 32 + quad * 8]);
                acc = __builtin_amdgcn_mfma_f32_16x16x32_bf16(av, bv, acc, 0, 0, 0);
            }
        }
        float* wout = wsf1 + (size_t)(m0 + quad * 4) * 512 + n0 + ln;
        wout[0] = acc[0];
        wout[512] = acc[1];
        wout[1024] = acc[2];
        wout[1536] = acc[3];
    }
}

// k_fc1s: fc1 LIF scan, linear strided reads + 16-deep prefetch.
__global__ __launch_bounds__(256) void k_fc1s(const float* __restrict__ wsf1,
                                              float* __restrict__ f1f) {
    int tid = blockIdx.x * 256 + threadIdx.x;   // 0..24575
    float u = 0.f, v = 0.f, rf = 0.f;
    float wbuf[16];
#pragma unroll
    for (int i = 0; i < 16; ++i) wbuf[i] = wsf1[(size_t)i * 24576 + tid];
    for (int tb = 0; tb < 128; tb += 16) {
#pragma unroll
        for (int j = 0; j < 16; ++j) {
            int t = tb + j;
            float w = wbuf[j];
            if (t + 16 < 128) wbuf[j] = wsf1[(size_t)(t + 16) * 24576 + tid];
            float s = dyn_step(w, u, v, rf);
            f1f[(size_t)t * 24576 + tid] = s;
        }
    }
}

// k_fc2w: fc2 wsum, parallel over t. Wave per (t,b).
__global__ __launch_bounds__(256) void k_fc2w(const float* __restrict__ f1f,
                                              const float* __restrict__ wfc2,
                                              float* __restrict__ wsf2) {
    int wv = blockIdx.x * 4 + (threadIdx.x >> 6);   // 0..6143
    int lane = threadIdx.x & 63;
    int b = wv % 48, t = wv / 48;
    int o = lane & 1, kq = lane >> 1;
    float acc = 0.f;
    if (t > 0) {
        const float* wp = wfc2 + o * 512 + kq * 16;
        const float* sp = f1f + (size_t)(t - 1) * 24576 + b * 512 + kq * 16;
#pragma unroll
        for (int i = 0; i < 16; ++i) acc += wp[i] * sp[i];
    }
#pragma unroll
    for (int m = 2; m < 64; m <<= 1) acc += __shfl_xor(acc, m, 64);
    if (lane < 2) wsf2[(size_t)t * 96 + b * 2 + o] = acc;
}

// k_fc2s: fc2 LIF scan + delay-shift into out [B,2,T]. 96 active threads.
__global__ __launch_bounds__(128) void k_fc2s(const float* __restrict__ wsf2,
                                              float* __restrict__ out) {
    int tid = threadIdx.x;
    if (tid >= 96) return;
    float* ob = out + tid * 128;       // tid = b*2+o
    ob[0] = 0.0f;
    float u = 0.f, v = 0.f, rf = 0.f;
    float wbuf[8];
#pragma unroll
    for (int i = 0; i < 8; ++i) wbuf[i] = wsf2[(size_t)i * 96 + tid];
    for (int tb = 0; tb < 128; tb += 8) {
#pragma unroll
        for (int j = 0; j < 8; ++j) {
            int t = tb + j;
            float w = wbuf[j];
            if (t + 8 < 128) wbuf[j] = wsf2[(size_t)(t + 8) * 96 + tid];
            float s = dyn_step(w, u, v, rf);
            if (t < 127) ob[t + 1] = s;
        }
    }
}

// ---------------------------------------------------------------------------
extern "C" void kernel_launch(void* const* d_in, const int* in_sizes, int n_in,
                              void* d_out, int out_size, void* d_ws, size_t ws_size,
                              hipStream_t stream) {
    const float* in   = (const float*)d_in[0];
    const float* w1   = (const float*)d_in[1];
    const float* w2   = (const float*)d_in[2];
    const float* w3   = (const float*)d_in[3];
    const float* wfc1 = (const float*)d_in[4];
    const float* wfc2 = (const float*)d_in[5];
    float* out = (float*)d_out;
    char* ws = (char*)d_ws;

    float*          slab = (float*)(ws);                       // 56,623,104 (conv wsums; wsf1 reuse)
    uint2*          xb   = (uint2*)(ws + 56623104);            //  2,752,512
    unsigned short* pb16 = (unsigned short*)(ws + 59375616);   //  1,376,256
    unsigned short* pb2  = (unsigned short*)(ws + 60751872);   //  1,572,864
    float*          f1f  = (float*)(ws + 64094208);            // 12,582,912
    unsigned short* a3   = (unsigned short*)(ws + 76677120);   //  3,538,944 [6144][288] bf16
    unsigned short* wb   = (unsigned short*)(ws + 80216064);   //    884,736 [3][288][512] bf16
    unsigned short* st1  = (unsigned short*)(ws + 81100800);   //    884,736 [3456 waves][128] u16
    unsigned short* st2  = (unsigned short*)(ws + 81985536);   //    442,368 [1728 waves][128] u16
    unsigned short* st3  = (unsigned short*)(ws + 82427904);   //    221,184 [864 waves][128] u16
    float*          wsf1 = (float*)(ws);                       // 12,582,912 (slab reuse, post-scan3)
    float*          wsf2 = (float*)(ws + 16777216);            //     49,152 (slab reuse, disjoint)
    // total 82,649,088 bytes

    hipMemsetAsync(xb, 0, 2752512, stream);     // pad rows 0/27
    hipMemsetAsync(pb16, 0, 1376256, stream);   // pad rows 0/13
    hipMemsetAsync(pb2, 0, 1572864, stream);    // pad rows 0/7
    hipMemsetAsync(a3, 0, 27648, stream);       // A rows t=0 (48*288 bf16)

    k_wsplit  <<<576, 256, 0, stream>>>(wfc1, wb);
    k_masks   <<<624, 256, 0, stream>>>(in, xb);
    k_wsum1<0><<<768, 576, 0, stream>>>(xb, w1, slab);
    k_scan1<0><<<432, 256, 0, stream>>>(slab, st1);
    k_wsum1<1><<<768, 576, 0, stream>>>(xb, w1, slab);
    k_scan1<1><<<432, 256, 0, stream>>>(slab, st1);
    k_mb1     <<<2304, 256, 0, stream>>>(st1, pb16);
    k_wsum2   <<<768, 576, 0, stream>>>(pb16, w2, slab);
    k_scan2   <<<192, 576, 0, stream>>>(slab, st2);
    k_mb2     <<<2304, 256, 0, stream>>>(st2, pb2);
    k_wsum3   <<<768, 576, 0, stream>>>(pb2, w3, slab);
    k_scan3   <<<216, 256, 0, stream>>>(slab, st3);
    k_mb3     <<<6858, 256, 0, stream>>>(st3, a3);
    k_fc1mm   <<<768, 256, 0, stream>>>(a3, wb, wsf1);
    k_fc1s    <<<96, 256, 0, stream>>>(wsf1, f1f);
    k_fc2w    <<<1536, 256, 0, stream>>>(f1f, wfc2, wsf2);
    k_fc2s    <<<1, 128, 0, stream>>>(wsf2, out);
}

// Round 15
// 418.280 us; speedup vs baseline: 1.2166x; 1.0408x over previous
//
#include <hip/hip_runtime.h>

// ---------------------------------------------------------------------------
// SNN forward, split-phase v5.4.
// wsum (parallel over t, LDS-LUT conv / MFMA fc) + scan (serial LIF).
// T16-tiled wsum slabs, sector-perfect register stores.
// v5.4: conv2 LUT vectorized across oc (validated on conv1 in v5.3) —
// pair 6-bit windows index float4 entries over the 4-oc quad; one thread
// computes 4 oc for 8 t. Window loads/extractions amortized 4x.
// ---------------------------------------------------------------------------

#define THETA 5120.0f

typedef __attribute__((ext_vector_type(8))) short bfrag;   // 8 bf16 (4 VGPRs)
typedef __attribute__((ext_vector_type(4))) float ffrag;   // 4 f32

__device__ __forceinline__ float dyn_step(float x, float& u, float& v, float& r) {
#pragma clang fp contract(off)
    u = 0.75f * u + 64.0f * x;          // current decay (1024/4096), W_SCALE=64
    float vn = 0.96875f * v + u;        // voltage decay (128/4096)
    vn = (r > 0.0f) ? 0.0f : vn;        // refractory clamp
    float s;
    if (vn >= THETA) { s = 1.0f; v = 0.0f; r = 1.0f; }
    else             { s = 0.0f; v = vn; r = fmaxf(r - 1.0f, 0.0f); }
    return s;
}

__device__ __forceinline__ float dpp_add_xor1(float x) {
    int y = __builtin_amdgcn_update_dpp(0, __float_as_int(x), 0xB1, 0xF, 0xF, true);
    return x + __int_as_float(y);
}
__device__ __forceinline__ float dpp_add_xor2(float x) {
    int y = __builtin_amdgcn_update_dpp(0, __float_as_int(x), 0x4E, 0xF, 0xF, true);
    return x + __int_as_float(y);
}

// compress bits at positions 4k (k=0..15) of a 64-bit word into 16 bits
__device__ __forceinline__ unsigned int compress4(unsigned long long x) {
    x &= 0x1111111111111111ull;
    x = (x | (x >> 3))  & 0x0303030303030303ull;
    x = (x | (x >> 6))  & 0x000F000F000F000Full;
    x = (x | (x >> 12)) & 0x000000FF000000FFull;
    x = (x | (x >> 24)) & 0xFFFFull;
    return (unsigned int)x;
}

__device__ __forceinline__ unsigned short f2bf(float f) {
    unsigned int u = __float_as_uint(f);
    unsigned int r = (u + 0x7FFFu + ((u >> 16) & 1u)) >> 16;   // RNE
    return (unsigned short)r;
}
__device__ __forceinline__ float bf2f(unsigned short b) {
    return __uint_as_float(((unsigned int)b) << 16);
}

__device__ __forceinline__ float f4_elem(float4 v, int j) {
    return (j == 0) ? v.x : (j == 1) ? v.y : (j == 2) ? v.z : v.w;
}

// ---------------------------------------------------------------------------
// k_masks: in [B=48,C=4,26,26,T=128] f32 -> xb uint2[t][b][pr][28 rows]
// ---------------------------------------------------------------------------
__global__ __launch_bounds__(256) void k_masks(const float* __restrict__ in,
                                               uint2* __restrict__ xb) {
    int wv = blockIdx.x * 4 + (threadIdx.x >> 6);
    int lane = threadIdx.x & 63;
    int y = wv % 26; int r = wv / 26;
    int pr = r & 1; int b = r >> 1;
    int ch = lane >> 5;
    int x = lane & 31;
    int act = x < 26;
    int xc = act ? x : 25;
    const float4* src = (const float4*)(in + (size_t)(((b * 4 + pr * 2 + ch) * 26 + y) * 26 + xc) * 128);
    uint2* dst = xb + ((size_t)b * 2 + pr) * 28 + (y + 1);
    for (int t4 = 0; t4 < 32; ++t4) {
        float4 f = src[t4];
#pragma unroll
        for (int k = 0; k < 4; ++k) {
            float fv = f4_elem(f, k);
            unsigned long long bal = __ballot(act && (fv != 0.0f));
            if (lane == 0) {
                unsigned int lo = ((unsigned int)bal & 0x03FFFFFFu) << 1;
                unsigned int hi = ((unsigned int)(bal >> 32) & 0x03FFFFFFu) << 1;
                dst[(size_t)(t4 * 4 + k) * 2688] = make_uint2(lo, hi);
            }
        }
    }
}

// ---------------------------------------------------------------------------
// k_wsum1: conv1 wsum (4->8ch, 5x5, 26->24), oc-quad H. Single-channel 5-bit
// windows -> float4 LUT over the oc quad. Block 576 = one b's pixels
// (quad-major); t-chunk 8 (grid 768). T16-tiled output, sector stores.
// ---------------------------------------------------------------------------
template<int H>
__global__ __launch_bounds__(576) void k_wsum1(const uint2* __restrict__ xb,
                                               const float* __restrict__ w1,
                                               float* __restrict__ ws) {
    __shared__ float wsh[400];
    __shared__ ffrag tbl4[660];           // [4ch][5ky][33] float4 (10.6 KB)
    int tid = threadIdx.x;
    int tch = blockIdx.x & 15;
    int b = blockIdx.x >> 4;              // 0..47
    if (tid < 400) wsh[tid] = w1[H * 400 + tid];   // [oc4][ch][5][5]
    __syncthreads();
    for (int e = tid; e < 660; e += 576) {
        int ch = e / 165;
        int rem = e % 165;
        int ky = rem / 33;
        int idx = rem % 33;
        ffrag val = {0.f, 0.f, 0.f, 0.f};
#pragma unroll
        for (int oc4 = 0; oc4 < 4; ++oc4) {
            float a = 0.f;
#pragma unroll
            for (int k = 0; k < 5; ++k)
                a += ((idx >> k) & 1) ? wsh[oc4 * 100 + ch * 25 + ky * 5 + k] : 0.f;
            val[oc4] = a;
        }
        tbl4[(ch * 5 + ky) * 33 + idx] = val;
    }
    __syncthreads();
    int q = tid >> 2, s = tid & 3;
    int ox = (q % 12) * 2 + (s & 1);
    int oy = (q / 12) * 2 + (s >> 1);
    int t0 = tch * 8;
    ffrag acc[8];
#pragma unroll
    for (int j = 0; j < 8; ++j) {
        int t = t0 + j;
        const uint2* rp = xb + ((size_t)t * 48 + b) * 56 + oy;
        ffrag a = {0.f, 0.f, 0.f, 0.f};
#pragma unroll
        for (int ky = 0; ky < 5; ++ky) {
            uint2 r0 = rp[ky];
            uint2 r1 = rp[28 + ky];
            a += tbl4[ky * 33 + (int)((r0.x >> ox) & 31u)];
            a += tbl4[(5 + ky) * 33 + (int)((r0.y >> ox) & 31u)];
            a += tbl4[(10 + ky) * 33 + (int)((r1.x >> ox) & 31u)];
            a += tbl4[(15 + ky) * 33 + (int)((r1.y >> ox) & 31u)];
        }
        acc[j] = a;
    }
    size_t tilebase = (size_t)(t0 >> 4) * 1769472 + (t0 & 15);
#pragma unroll
    for (int oc4 = 0; oc4 < 4; ++oc4) {
        float* wp = ws + tilebase + (size_t)((b * 4 + oc4) * 576 + tid) * 16;
        *(float4*)(wp)     = make_float4(acc[0][oc4], acc[1][oc4], acc[2][oc4], acc[3][oc4]);
        *(float4*)(wp + 4) = make_float4(acc[4][oc4], acc[5][oc4], acc[6][oc4], acc[7][oc4]);
    }
}

// ---------------------------------------------------------------------------
// k_scan1: conv1 LIF + pool1 LIF, oc half H. Wave = 64 neurons = 16 quads.
// T16-tiled reads. Staging st1[(H*1728 + wave)*128 + t]. 1728 waves/half.
// ---------------------------------------------------------------------------
template<int H>
__global__ __launch_bounds__(256) void k_scan1(const float* __restrict__ ws,
                                               unsigned short* __restrict__ st1) {
    int wv = blockIdx.x * 4 + (threadIdx.x >> 6);   // 0..1727
    int lane = threadIdx.x & 63;
    const float* bp = ws + (size_t)(wv * 64 + lane) * 16;
    unsigned short* so = st1 + ((size_t)(H * 1728 + wv)) * 128;
    float u = 0.f, v = 0.f, rf = 0.f;
    float pu = 0.f, pv = 0.f, prf = 0.f;
    float sp = 0.f;
    unsigned int mb[4];
    float4 cur[4], nxt[4];
#pragma unroll
    for (int i = 0; i < 4; ++i) cur[i] = *(const float4*)(bp + i * 4);
    for (int tb = 0; tb < 8; ++tb) {
        if (tb < 7) {
            const float* np = bp + (size_t)(tb + 1) * 1769472;
#pragma unroll
            for (int i = 0; i < 4; ++i) nxt[i] = *(const float4*)(np + i * 4);
        }
#pragma unroll
        for (int j = 0; j < 16; ++j) {
            int t = tb * 16 + j;
            float w = f4_elem(cur[j >> 2], j & 3);
            float cnt = dpp_add_xor2(dpp_add_xor1(sp));
            float ps = dyn_step(88.0f * cnt, pu, pv, prf);
            unsigned long long bal = __ballot(((lane & 3) == 0) && (ps > 0.5f));
            unsigned int m = compress4(bal);
            int sl = (t >> 1) & 3;
            mb[sl] = (t & 1) ? (mb[sl] | (m << 16)) : m;
            if ((t & 7) == 7 && lane == 0)
                *(uint4*)(so + (t & ~7)) = make_uint4(mb[0], mb[1], mb[2], mb[3]);
            sp = dyn_step(w, u, v, rf);
        }
        if (tb < 7) {
#pragma unroll
            for (int i = 0; i < 4; ++i) cur[i] = nxt[i];
        }
    }
}

// k_mb1: st1 -> pb16 row masks [t][b][y+1][oc] (12 bits << 1). 589824 thr.
__global__ __launch_bounds__(256) void k_mb1(const unsigned short* __restrict__ st1,
                                             unsigned short* __restrict__ pb16) {
    int gid = blockIdx.x * 256 + threadIdx.x;
    int oc = gid & 7; int r = gid >> 3;
    int y = r % 12; r /= 12;
    int b = r % 48; int t = r / 48;
    int base = (oc >> 2) * 1728 + (b * 4 + (oc & 3)) * 9;
    int Q0 = y * 12;
    int w0 = Q0 >> 4, off = Q0 & 15;
    unsigned int v0 = st1[(size_t)(base + w0) * 128 + t];
    unsigned int v1 = (off > 4) ? (unsigned int)st1[(size_t)(base + w0 + 1) * 128 + t] : 0u;
    unsigned int m = ((v0 >> off) | (v1 << (16 - off))) & 0xFFFu;
    pb16[((size_t)(t * 48 + b) * 14 + y + 1) * 8 + oc] = (unsigned short)(m << 1);
}

// ---------------------------------------------------------------------------
// k_wsum2: conv2 wsum (8->16ch, 3x3, 12->12), oc-quad vectorized.
// Pair 6-bit windows -> float4 LUT over the oc quad: tbl4[(pr*3+ky)*71+idx]
// (13.6 KB). Block = (b, ocg, tch): 576 thr = 4 tq x 144 pix; one thread =
// one pixel, 4 oc, 8 t. Grid 768 = 48b x 4ocg x 4tch. T16-tiled output.
// ---------------------------------------------------------------------------
__global__ __launch_bounds__(576) void k_wsum2(const unsigned short* __restrict__ pb16,
                                               const float* __restrict__ w2,
                                               float* __restrict__ ws) {
    __shared__ float wsh[288];
    __shared__ ffrag tbl4[852];           // [4pr][3ky][71] float4 (13.6 KB)
    int tid = threadIdx.x;
    int tch = blockIdx.x & 3;
    int r = blockIdx.x >> 2;
    int ocg = r & 3; int b = r >> 2;      // b 0..47, ocg 0..3
    if (tid < 288) wsh[tid] = w2[(ocg * 4 + tid / 72) * 72 + (tid % 72)];
    __syncthreads();
    for (int e = tid; e < 852; e += 576) {
        int pr = e / 213;                 // 3*71
        int rem = e % 213;
        int ky = rem / 71;
        int idx = rem % 71;
        int lo = idx % 9, hi = idx / 9;   // valid windows have lo<8, hi<8
        ffrag val = {0.f, 0.f, 0.f, 0.f};
#pragma unroll
        for (int oc4 = 0; oc4 < 4; ++oc4) {
            float a = 0.f;
#pragma unroll
            for (int k = 0; k < 3; ++k)
                a += ((lo >> k) & 1) ? wsh[oc4 * 72 + (2 * pr) * 9 + ky * 3 + k] : 0.f;
#pragma unroll
            for (int k = 0; k < 3; ++k)
                a += ((hi >> k) & 1) ? wsh[oc4 * 72 + (2 * pr + 1) * 9 + ky * 3 + k] : 0.f;
            val[oc4] = a;
        }
        tbl4[(pr * 3 + ky) * 71 + idx] = val;
    }
    __syncthreads();
    int tq = tid / 144;
    int pix = tid % 144;
    int q = pix >> 2, s = pix & 3;
    int ox = (q % 6) * 2 + (s & 1);
    int oy = (q / 6) * 2 + (s >> 1);
    int t0 = tch * 32 + tq * 8;
    ffrag acc[8];
#pragma unroll
    for (int j = 0; j < 8; ++j) {
        int t = t0 + j;
        ffrag a = {0.f, 0.f, 0.f, 0.f};
        if (t > 0) {
            const uint4* rp = (const uint4*)(pb16 + (((size_t)(t - 1) * 48 + b) * 14 + oy) * 8);
#pragma unroll
            for (int ky = 0; ky < 3; ++ky) {
                uint4 row = rp[ky];
                unsigned int wd[4] = {row.x, row.y, row.z, row.w};
#pragma unroll
                for (int pr = 0; pr < 4; ++pr) {
                    unsigned int lo = (wd[pr] >> ox) & 7u;
                    unsigned int hi = (wd[pr] >> (16 + ox)) & 7u;
                    a += tbl4[(pr * 3 + ky) * 71 + (int)(lo + 9u * hi)];
                }
            }
        }
        acc[j] = a;
    }
    size_t tilebase = (size_t)(t0 >> 4) * 1769472 + (t0 & 15);
#pragma unroll
    for (int oc4 = 0; oc4 < 4; ++oc4) {
        int neuron = (b * 16 + ocg * 4 + oc4) * 144 + pix;
        float* wp = ws + tilebase + (size_t)neuron * 16;
        *(float4*)(wp)     = make_float4(acc[0][oc4], acc[1][oc4], acc[2][oc4], acc[3][oc4]);
        *(float4*)(wp + 4) = make_float4(acc[4][oc4], acc[5][oc4], acc[6][oc4], acc[7][oc4]);
    }
}

// ---------------------------------------------------------------------------
// k_scan2: conv2 LIF + pool2 LIF. Block 576 = 4 images (9 waves); wave = 16
// quads. T16-tiled reads. Staging st2[(g4*9 + wloc)*128 + t]. 1728 waves.
// ---------------------------------------------------------------------------
__global__ __launch_bounds__(576) void k_scan2(const float* __restrict__ ws,
                                               unsigned short* __restrict__ st2) {
    int tid = threadIdx.x;
    int wloc = tid >> 6, lane = tid & 63;
    int g4 = blockIdx.x;                  // 0..191
    const float* bp = ws + (size_t)(g4 * 576 + tid) * 16;
    unsigned short* so = st2 + ((size_t)(g4 * 9 + wloc)) * 128;
    float u = 0.f, v = 0.f, rf = 0.f;
    float pu = 0.f, pv = 0.f, prf = 0.f;
    float sp = 0.f;
    unsigned int mb[4];
    float4 cur[4], nxt[4];
#pragma unroll
    for (int i = 0; i < 4; ++i) cur[i] = *(const float4*)(bp + i * 4);
    for (int tb = 0; tb < 8; ++tb) {
        if (tb < 7) {
            const float* np = bp + (size_t)(tb + 1) * 1769472;
#pragma unroll
            for (int i = 0; i < 4; ++i) nxt[i] = *(const float4*)(np + i * 4);
        }
#pragma unroll
        for (int j = 0; j < 16; ++j) {
            int t = tb * 16 + j;
            float w = f4_elem(cur[j >> 2], j & 3);
            float cnt = dpp_add_xor2(dpp_add_xor1(sp));
            float ps = dyn_step(88.0f * cnt, pu, pv, prf);
            unsigned long long bal = __ballot(((lane & 3) == 0) && (ps > 0.5f));
            unsigned int m = compress4(bal);
            int sl = (t >> 1) & 3;
            mb[sl] = (t & 1) ? (mb[sl] | (m << 16)) : m;
            if ((t & 7) == 7 && lane == 0)
                *(uint4*)(so + (t & ~7)) = make_uint4(mb[0], mb[1], mb[2], mb[3]);
            sp = dyn_step(w, u, v, rf);
        }
        if (tb < 7) {
#pragma unroll
            for (int i = 0; i < 4; ++i) cur[i] = nxt[i];
        }
    }
}

// k_mb2: st2 -> pb2 row masks [t][b][y+1][oc] (6 bits << 1). 589824 thr.
__global__ __launch_bounds__(256) void k_mb2(const unsigned short* __restrict__ st2,
                                             unsigned short* __restrict__ pb2) {
    int gid = blockIdx.x * 256 + threadIdx.x;
    int oc = gid & 15; int r = gid >> 4;
    int y = r % 6; r /= 6;
    int b = r % 48; int t = r / 48;
    int img = b * 16 + oc;
    int g4 = img >> 2, lI = img & 3;
    int Q0 = lI * 36 + y * 6;
    int w0 = Q0 >> 4, off = Q0 & 15;
    unsigned int v0 = st2[(size_t)(g4 * 9 + w0) * 128 + t];
    unsigned int v1 = (off > 10) ? (unsigned int)st2[(size_t)(g4 * 9 + w0 + 1) * 128 + t] : 0u;
    unsigned int m = ((v0 >> off) | (v1 << (16 - off))) & 0x3Fu;
    pb2[((size_t)(t * 48 + b) * 8 + y + 1) * 16 + oc] = (unsigned short)(m << 1);
}

// ---------------------------------------------------------------------------
// k_wsum3: conv3 wsum (16->32ch, 3x3, 6->6). QUAD-MAJOR. t-chunk 16 (grid
// 768). T16-tiled output (tile = tch), register acc + sector stores.
// ---------------------------------------------------------------------------
__global__ __launch_bounds__(576) void k_wsum3(const unsigned short* __restrict__ pb2,
                                               const float* __restrict__ w3,
                                               float* __restrict__ ws) {
    __shared__ float wsh[576];
    __shared__ float tbl[6816];
    int tid = threadIdx.x;
    int tch = blockIdx.x & 7;
    int gb = blockIdx.x >> 3;             // 0..95 = ocg*12 + bg
    int ocg = gb / 12, bg = gb % 12;
    {
        int oc_t = ocg * 4 + tid / 144;
        wsh[tid] = w3[oc_t * 144 + (tid % 144)];
    }
    __syncthreads();
    for (int e = tid; e < 6144; e += 576) {
        int osel = e / 1536;
        int pr = (e / 192) % 8;
        int ky = (e / 64) % 3;
        int i = e & 63;
        int lo = i & 7, hi = i >> 3;
        float val = 0.f;
#pragma unroll
        for (int k = 0; k < 3; ++k)
            val += ((lo >> k) & 1) ? wsh[osel * 144 + (2 * pr) * 9 + ky * 3 + k] : 0.f;
#pragma unroll
        for (int k = 0; k < 3; ++k)
            val += ((hi >> k) & 1) ? wsh[osel * 144 + (2 * pr + 1) * 9 + ky * 3 + k] : 0.f;
        tbl[osel * 1704 + (pr * 3 + ky) * 71 + lo + 9 * hi] = val;
    }
    __syncthreads();
    int osel = tid / 144;
    int rem = tid % 144;
    int bsel = rem / 36;
    int pix = rem % 36;
    int q = pix >> 2, s = pix & 3;
    int ox = (q % 3) * 2 + (s & 1);
    int oy = (q / 3) * 2 + (s >> 1);
    int oc = ocg * 4 + osel;
    int b = bg * 4 + bsel;
    const float* tb = tbl + osel * 1704;
    float* op = ws + (size_t)tch * 884736 + (size_t)((b * 32 + oc) * 36 + pix) * 16;
    for (int sub = 0; sub < 2; ++sub) {
        int t0 = tch * 16 + sub * 8;
        float acc[8];
#pragma unroll
        for (int j = 0; j < 8; ++j) {
            int t = t0 + j;
            float a = 0.f;
            if (t > 0) {
                const uint4* rp = (const uint4*)(pb2 + (((size_t)(t - 1) * 48 + b) * 8 + oy) * 16);
#pragma unroll
                for (int ky = 0; ky < 3; ++ky) {
                    uint4 rA = rp[ky * 2];
                    uint4 rB = rp[ky * 2 + 1];
                    unsigned int wd[8] = {rA.x, rA.y, rA.z, rA.w, rB.x, rB.y, rB.z, rB.w};
#pragma unroll
                    for (int pr = 0; pr < 8; ++pr) {
                        unsigned int lo = (wd[pr] >> ox) & 7u;
                        unsigned int hi = (wd[pr] >> (16 + ox)) & 7u;
                        a += tb[(pr * 3 + ky) * 71 + (int)(lo + 9u * hi)];
                    }
                }
            }
            acc[j] = a;
        }
        float* wp = op + sub * 8;
        *(float4*)(wp)     = make_float4(acc[0], acc[1], acc[2], acc[3]);
        *(float4*)(wp + 4) = make_float4(acc[4], acc[5], acc[6], acc[7]);
    }
}

// ---------------------------------------------------------------------------
// k_scan3: conv3 LIF + pool3 LIF. 864 waves; T16-tiled reads; staging
// st3[wave*128 + t].
// ---------------------------------------------------------------------------
__global__ __launch_bounds__(256) void k_scan3(const float* __restrict__ ws,
                                               unsigned short* __restrict__ st3) {
    int wv = blockIdx.x * 4 + (threadIdx.x >> 6);   // 0..863
    int lane = threadIdx.x & 63;
    const float* bp = ws + (size_t)(wv * 64 + lane) * 16;
    unsigned short* so = st3 + (size_t)wv * 128;
    float u = 0.f, v = 0.f, rf = 0.f;
    float pu = 0.f, pv = 0.f, prf = 0.f;
    float sp = 0.f;
    unsigned int mb[4];
    float4 cur[4], nxt[4];
#pragma unroll
    for (int i = 0; i < 4; ++i) cur[i] = *(const float4*)(bp + i * 4);
    for (int tb = 0; tb < 8; ++tb) {
        if (tb < 7) {
            const float* np = bp + (size_t)(tb + 1) * 884736;
#pragma unroll
            for (int i = 0; i < 4; ++i) nxt[i] = *(const float4*)(np + i * 4);
        }
#pragma unroll
        for (int j = 0; j < 16; ++j) {
            int t = tb * 16 + j;
            float w = f4_elem(cur[j >> 2], j & 3);
            float cnt = dpp_add_xor2(dpp_add_xor1(sp));
            float ps = dyn_step(88.0f * cnt, pu, pv, prf);
            unsigned long long bal = __ballot(((lane & 3) == 0) && (ps > 0.5f));
            unsigned int m = compress4(bal);
            int sl = (t >> 1) & 3;
            mb[sl] = (t & 1) ? (mb[sl] | (m << 16)) : m;
            if ((t & 7) == 7 && lane == 0)
                *(uint4*)(so + (t & ~7)) = make_uint4(mb[0], mb[1], mb[2], mb[3]);
            sp = dyn_step(w, u, v, rf);
        }
        if (tb < 7) {
#pragma unroll
            for (int i = 0; i < 4; ++i) cur[i] = nxt[i];
        }
    }
}

// k_mb3: st3 -> bf16 A-matrix a3[(t+1)*13824 + G] (delay-shift folded).
__global__ __launch_bounds__(256) void k_mb3(const unsigned short* __restrict__ st3,
                                             unsigned short* __restrict__ a3) {
    int gid = blockIdx.x * 256 + threadIdx.x;
    if (gid >= 1755648) return;
    int G = gid % 13824, t = gid / 13824;
    unsigned int bit = ((unsigned int)st3[(size_t)(G >> 4) * 128 + t] >> (G & 15)) & 1u;
    a3[(size_t)(t + 1) * 13824 + G] = bit ? 0x3F80 : 0;
}

// ---------------------------------------------------------------------------
// k_wsplit: wfc1[512][288] f32 -> wb[3][288][512] bf16 (bf16x3 split).
// ---------------------------------------------------------------------------
__global__ __launch_bounds__(256) void k_wsplit(const float* __restrict__ wfc1,
                                                unsigned short* __restrict__ wb) {
    int gid = blockIdx.x * 256 + threadIdx.x;
    int o = gid / 288, k = gid % 288;
    float w = wfc1[gid];
    unsigned short b0 = f2bf(w);
    float r1 = w - bf2f(b0);
    unsigned short b1 = f2bf(r1);
    float r2 = r1 - bf2f(b1);
    unsigned short b2 = f2bf(r2);
    wb[(size_t)k * 512 + o] = b0;
    wb[(size_t)147456 + k * 512 + o] = b1;
    wb[(size_t)294912 + k * 512 + o] = b2;
}

// ---------------------------------------------------------------------------
// k_fc1mm: wsf1[m][o] = A x W via mfma_f32_16x16x32_bf16. Linear coalesced
// epilogue (wsf1[m*512+n]).
// ---------------------------------------------------------------------------
__global__ __launch_bounds__(256) void k_fc1mm(const unsigned short* __restrict__ a3,
                                               const unsigned short* __restrict__ wb,
                                               float* __restrict__ wsf1) {
    __shared__ unsigned short Bs[16 * 872];
    int tid = threadIdx.x;
    int nt = blockIdx.x & 31;
    int mc = blockIdx.x >> 5;
    int n0 = nt * 16;
    for (int idx = tid; idx < 13824; idx += 256) {
        int kp = idx >> 4;
        int n = idx & 15;
        Bs[n * 872 + kp] = wb[(size_t)kp * 512 + n0 + n];
    }
    __syncthreads();
    int wave = tid >> 6;
    int lane = tid & 63;
    int ln = lane & 15, quad = lane >> 4;
#pragma unroll
    for (int i = 0; i < 4; ++i) {
        int m0 = (mc * 16 + wave * 4 + i) * 16;
        const unsigned short* arow = a3 + (size_t)(m0 + ln) * 288 + quad * 8;
        ffrag acc = {0.f, 0.f, 0.f, 0.f};
#pragma unroll
        for (int kb = 0; kb < 9; ++kb) {
            bfrag av = *(const bfrag*)(arow + kb * 32);
#pragma unroll
            for (int c = 0; c < 3; ++c) {
                bfrag bv = *(const bfrag*)(&Bs[ln * 872 + c * 288 + kb * 32 + quad * 8]);
                acc = __builtin_amdgcn_mfma_f32_16x16x32_bf16(av, bv, acc, 0, 0, 0);
            }
        }
        float* wout = wsf1 + (size_t)(m0 + quad * 4) * 512 + n0 + ln;
        wout[0] = acc[0];
        wout[512] = acc[1];
        wout[1024] = acc[2];
        wout[1536] = acc[3];
    }
}

// k_fc1s: fc1 LIF scan, linear strided reads + 16-deep prefetch.
__global__ __launch_bounds__(256) void k_fc1s(const float* __restrict__ wsf1,
                                              float* __restrict__ f1f) {
    int tid = blockIdx.x * 256 + threadIdx.x;   // 0..24575
    float u = 0.f, v = 0.f, rf = 0.f;
    float wbuf[16];
#pragma unroll
    for (int i = 0; i < 16; ++i) wbuf[i] = wsf1[(size_t)i * 24576 + tid];
    for (int tb = 0; tb < 128; tb += 16) {
#pragma unroll
        for (int j = 0; j < 16; ++j) {
            int t = tb + j;
            float w = wbuf[j];
            if (t + 16 < 128) wbuf[j] = wsf1[(size_t)(t + 16) * 24576 + tid];
            float s = dyn_step(w, u, v, rf);
            f1f[(size_t)t * 24576 + tid] = s;
        }
    }
}

// k_fc2w: fc2 wsum, parallel over t. Wave per (t,b).
__global__ __launch_bounds__(256) void k_fc2w(const float* __restrict__ f1f,
                                              const float* __restrict__ wfc2,
                                              float* __restrict__ wsf2) {
    int wv = blockIdx.x * 4 + (threadIdx.x >> 6);   // 0..6143
    int lane = threadIdx.x & 63;
    int b = wv % 48, t = wv / 48;
    int o = lane & 1, kq = lane >> 1;
    float acc = 0.f;
    if (t > 0) {
        const float* wp = wfc2 + o * 512 + kq * 16;
        const float* sp = f1f + (size_t)(t - 1) * 24576 + b * 512 + kq * 16;
#pragma unroll
        for (int i = 0; i < 16; ++i) acc += wp[i] * sp[i];
    }
#pragma unroll
    for (int m = 2; m < 64; m <<= 1) acc += __shfl_xor(acc, m, 64);
    if (lane < 2) wsf2[(size_t)t * 96 + b * 2 + o] = acc;
}

// k_fc2s: fc2 LIF scan + delay-shift into out [B,2,T]. 96 active threads.
__global__ __launch_bounds__(128) void k_fc2s(const float* __restrict__ wsf2,
                                              float* __restrict__ out) {
    int tid = threadIdx.x;
    if (tid >= 96) return;
    float* ob = out + tid * 128;       // tid = b*2+o
    ob[0] = 0.0f;
    float u = 0.f, v = 0.f, rf = 0.f;
    float wbuf[8];
#pragma unroll
    for (int i = 0; i < 8; ++i) wbuf[i] = wsf2[(size_t)i * 96 + tid];
    for (int tb = 0; tb < 128; tb += 8) {
#pragma unroll
        for (int j = 0; j < 8; ++j) {
            int t = tb + j;
            float w = wbuf[j];
            if (t + 8 < 128) wbuf[j] = wsf2[(size_t)(t + 8) * 96 + tid];
            float s = dyn_step(w, u, v, rf);
            if (t < 127) ob[t + 1] = s;
        }
    }
}

// ---------------------------------------------------------------------------
extern "C" void kernel_launch(void* const* d_in, const int* in_sizes, int n_in,
                              void* d_out, int out_size, void* d_ws, size_t ws_size,
                              hipStream_t stream) {
    const float* in   = (const float*)d_in[0];
    const float* w1   = (const float*)d_in[1];
    const float* w2   = (const float*)d_in[2];
    const float* w3   = (const float*)d_in[3];
    const float* wfc1 = (const float*)d_in[4];
    const float* wfc2 = (const float*)d_in[5];
    float* out = (float*)d_out;
    char* ws = (char*)d_ws;

    float*          slab = (float*)(ws);                       // 56,623,104 (conv wsums; wsf1 reuse)
    uint2*          xb   = (uint2*)(ws + 56623104);            //  2,752,512
    unsigned short* pb16 = (unsigned short*)(ws + 59375616);   //  1,376,256
    unsigned short* pb2  = (unsigned short*)(ws + 60751872);   //  1,572,864
    float*          f1f  = (float*)(ws + 64094208);            // 12,582,912
    unsigned short* a3   = (unsigned short*)(ws + 76677120);   //  3,538,944 [6144][288] bf16
    unsigned short* wb   = (unsigned short*)(ws + 80216064);   //    884,736 [3][288][512] bf16
    unsigned short* st1  = (unsigned short*)(ws + 81100800);   //    884,736 [3456 waves][128] u16
    unsigned short* st2  = (unsigned short*)(ws + 81985536);   //    442,368 [1728 waves][128] u16
    unsigned short* st3  = (unsigned short*)(ws + 82427904);   //    221,184 [864 waves][128] u16
    float*          wsf1 = (float*)(ws);                       // 12,582,912 (slab reuse, post-scan3)
    float*          wsf2 = (float*)(ws + 16777216);            //     49,152 (slab reuse, disjoint)
    // total 82,649,088 bytes

    hipMemsetAsync(xb, 0, 2752512, stream);     // pad rows 0/27
    hipMemsetAsync(pb16, 0, 1376256, stream);   // pad rows 0/13
    hipMemsetAsync(pb2, 0, 1572864, stream);    // pad rows 0/7
    hipMemsetAsync(a3, 0, 27648, stream);       // A rows t=0 (48*288 bf16)

    k_wsplit  <<<576, 256, 0, stream>>>(wfc1, wb);
    k_masks   <<<624, 256, 0, stream>>>(in, xb);
    k_wsum1<0><<<768, 576, 0, stream>>>(xb, w1, slab);
    k_scan1<0><<<432, 256, 0, stream>>>(slab, st1);
    k_wsum1<1><<<768, 576, 0, stream>>>(xb, w1, slab);
    k_scan1<1><<<432, 256, 0, stream>>>(slab, st1);
    k_mb1     <<<2304, 256, 0, stream>>>(st1, pb16);
    k_wsum2   <<<768, 576, 0, stream>>>(pb16, w2, slab);
    k_scan2   <<<192, 576, 0, stream>>>(slab, st2);
    k_mb2     <<<2304, 256, 0, stream>>>(st2, pb2);
    k_wsum3   <<<768, 576, 0, stream>>>(pb2, w3, slab);
    k_scan3   <<<216, 256, 0, stream>>>(slab, st3);
    k_mb3     <<<6858, 256, 0, stream>>>(st3, a3);
    k_fc1mm   <<<768, 256, 0, stream>>>(a3, wb, wsf1);
    k_fc1s    <<<96, 256, 0, stream>>>(wsf1, f1f);
    k_fc2w    <<<1536, 256, 0, stream>>>(f1f, wfc2, wsf2);
    k_fc2s    <<<1, 128, 0, stream>>>(wsf2, out);
}